// Round 3
// baseline (11518.317 us; speedup 1.0000x reference)
//
#include <hip/hip_runtime.h>
#include <hip/hip_bf16.h>

typedef __hip_bfloat16 bf16;

#define BT 8
#define HH 64
#define WW 64
#define NSP (HH*WW)          // 4096 spatial per batch
#define DD 512
#define CF 128
#define IC 640
#define NG 64                // windows per batch
#define NM 64                // global tokens per batch
#define EPS 1e-5f

static __device__ __forceinline__ float b2f(bf16 v) { return __bfloat162float(v); }
static __device__ __forceinline__ bf16 f2b(float v) { return __float2bfloat16(v); }

// ---------------- dtype detector ----------------
// Interpret first 4096 32-bit words of x as fp32. True fp32 N(0,1) data:
// ~100% have |v| in (1e-5, 1e4). Packed bf16 pairs: fp32 exponent field is
// the high bf16's exponent bits shifted -> |v| lands out of range ~always.
__global__ void detect_dtype(const void* __restrict__ x, int* __restrict__ flag) {
    __shared__ int cnt;
    if (threadIdx.x == 0) cnt = 0;
    __syncthreads();
    const unsigned* w = (const unsigned*)x;
    int local = 0;
    for (int i = threadIdx.x; i < 4096; i += 256) {
        float v = __uint_as_float(w[i]);
        float a = fabsf(v);
        if (a > 1e-5f && a < 1e4f) local++;   // false for NaN
    }
    atomicAdd(&cnt, local);
    __syncthreads();
    if (threadIdx.x == 0) *flag = (cnt > 2048) ? 1 : 0;   // 1 = fp32, 0 = bf16
}

// ---------------- canonicalize all 20 weight tensors to bf16 ----------------
#define NW 20
struct WTab {
    const void* src[NW];
    int cnt[NW];
    int pre[NW + 1];   // prefix offsets into canonical buffer
};

__global__ void convert_weights(WTab t, const int* __restrict__ flag,
                                bf16* __restrict__ dst, int total) {
    int fp32 = *flag;
    for (int idx = blockIdx.x * blockDim.x + threadIdx.x; idx < total;
         idx += gridDim.x * blockDim.x) {
        int seg = 0;
        #pragma unroll
        for (int i = 0; i < NW; ++i) if (idx >= t.pre[i + 1]) seg = i + 1;
        int local = idx - t.pre[seg];
        bf16 v;
        if (fp32) v = f2b(((const float*)t.src[seg])[local]);
        else      v = ((const bf16*)t.src[seg])[local];
        dst[idx] = v;
    }
}

// ---------------- assemble qk = [x | f], dual dtype ----------------
__global__ void assemble_qk(const void* __restrict__ xv, const void* __restrict__ fv,
                            const int* __restrict__ flag, bf16* __restrict__ qk, int rows) {
    int fp32 = *flag;
    long long total = (long long)rows * IC;
    for (long long i = (long long)blockIdx.x * blockDim.x + threadIdx.x; i < total;
         i += (long long)gridDim.x * blockDim.x) {
        int row = (int)(i / IC);
        int c = (int)(i % IC);
        bf16 v;
        if (c < DD) {
            long long si = (long long)row * DD + c;
            v = fp32 ? f2b(((const float*)xv)[si]) : ((const bf16*)xv)[si];
        } else {
            long long si = (long long)row * CF + (c - DD);
            v = fp32 ? f2b(((const float*)fv)[si]) : ((const bf16*)fv)[si];
        }
        qk[i] = v;
    }
}

// ---------------- store output, dual dtype ----------------
__global__ void store_out(const bf16* __restrict__ outc, void* __restrict__ dout,
                          const int* __restrict__ flag, long long n, long long off) {
    int fp32 = *flag;
    for (long long i = (long long)blockIdx.x * blockDim.x + threadIdx.x; i < n;
         i += (long long)gridDim.x * blockDim.x) {
        if (fp32) ((float*)dout)[off + i] = b2f(outc[i]);
        else      ((bf16*)dout)[off + i] = outc[i];
    }
}

// ---------------- reweight: qk[:,512+j] *= fw[:,j] ----------------
__global__ void reweight_f(bf16* __restrict__ qk, const bf16* __restrict__ fw, int rows) {
    long long i = (long long)blockIdx.x * blockDim.x + threadIdx.x;
    long long total = (long long)rows * CF;
    if (i >= total) return;
    int row = (int)(i / CF);
    int j = (int)(i % CF);
    long long qi = (long long)row * IC + DD + j;
    qk[qi] = f2b(b2f(qk[qi]) * b2f(fw[i]));
}

// ---------------- depthwise conv, 8x8 stride 8 ----------------
// src rows have stride ldr; uses channels [0, C). dst [bcount, 64, C]
__global__ void dwconv_kernel(const bf16* __restrict__ src, int ldr, int C,
                              const bf16* __restrict__ w, const bf16* __restrict__ bias,
                              bf16* __restrict__ dst) {
    int bm = blockIdx.x;          // 0..bcount*64-1
    int b = bm >> 6;
    int m = bm & 63;
    int my = m >> 3, mx = m & 7;
    const bf16* sb = src + (long long)b * NSP * ldr;
    for (int c = threadIdx.x; c < C; c += blockDim.x) {
        float acc = b2f(bias[c]);
        #pragma unroll
        for (int ky = 0; ky < 8; ++ky) {
            #pragma unroll
            for (int kx = 0; kx < 8; ++kx) {
                int pos = (my * 8 + ky) * WW + mx * 8 + kx;
                acc += b2f(sb[(long long)pos * ldr + c]) * b2f(w[c * 64 + ky * 8 + kx]);
            }
        }
        dst[(long long)bm * C + c] = f2b(acc);
    }
}

// ---------------- per-row LN stats (mean, rstd) over K cols, row stride lda ----------------
__global__ void stats_kernel(const bf16* __restrict__ X, int lda, float* __restrict__ stats,
                             int rows, int K) {
    int gt = blockIdx.x * blockDim.x + threadIdx.x;
    int wid = gt >> 6;
    int lane = gt & 63;
    if (wid >= rows) return;
    const bf16* p = X + (long long)wid * lda;
    float s = 0.f, ss = 0.f;
    for (int k = lane; k < K; k += 64) {
        float v = b2f(p[k]);
        s += v; ss += v * v;
    }
    #pragma unroll
    for (int off = 32; off > 0; off >>= 1) {
        s  += __shfl_down(s,  off, 64);
        ss += __shfl_down(ss, off, 64);
    }
    if (lane == 0) {
        float m = s / K;
        float var = ss / K - m * m;
        stats[wid * 2]     = m;
        stats[wid * 2 + 1] = rsqrtf(var + EPS);
    }
}

// ---------------- tiled GEMM with optional fused LN on A and epilogue ----------------
// C[M,N] = op(A) @ B + bias ; op(A)[r,k] = stats ? (A[r,k]-mean[r])*rstd[r]*g[k]+beta[k] : A[r,k]
// A row stride = lda. mode 0: plain (+bias) ; mode 1: sigmoid(acc+bias)
#define TM 64
#define TN 64
#define TK 32
__global__ void gemm_ln(const bf16* __restrict__ A, int lda, const float* __restrict__ stats,
                        const bf16* __restrict__ lng, const bf16* __restrict__ lnb,
                        const bf16* __restrict__ B, const bf16* __restrict__ bias,
                        bf16* __restrict__ C, int M, int N, int K, int mode) {
    __shared__ float As[TK][TM + 1];
    __shared__ float Bs[TK][TN + 1];
    int bm = blockIdx.y * TM;
    int bn = blockIdx.x * TN;
    int tid = threadIdx.x;
    int tx = tid & 15, ty = tid >> 4;
    float acc[4][4] = {};
    for (int k0 = 0; k0 < K; k0 += TK) {
        #pragma unroll
        for (int i = 0; i < 8; ++i) {
            int idx = tid + i * 256;
            int r = idx >> 5, kk = idx & 31;
            int row = bm + r;
            int kg = k0 + kk;
            float a = b2f(A[(long long)row * lda + kg]);
            if (stats) {
                float mean = stats[row * 2], rstd = stats[row * 2 + 1];
                a = (a - mean) * rstd * b2f(lng[kg]) + b2f(lnb[kg]);
            }
            As[kk][r] = a;
        }
        #pragma unroll
        for (int i = 0; i < 8; ++i) {
            int idx = tid + i * 256;
            int kk = idx >> 6, c = idx & 63;
            Bs[kk][c] = b2f(B[(long long)(k0 + kk) * N + bn + c]);
        }
        __syncthreads();
        #pragma unroll
        for (int kk = 0; kk < TK; ++kk) {
            float ar[4], br[4];
            #pragma unroll
            for (int i = 0; i < 4; ++i) ar[i] = As[kk][ty * 4 + i];
            #pragma unroll
            for (int j = 0; j < 4; ++j) br[j] = Bs[kk][tx * 4 + j];
            #pragma unroll
            for (int i = 0; i < 4; ++i)
                #pragma unroll
                for (int j = 0; j < 4; ++j)
                    acc[i][j] += ar[i] * br[j];
        }
        __syncthreads();
    }
    #pragma unroll
    for (int i = 0; i < 4; ++i) {
        int row = bm + ty * 4 + i;
        #pragma unroll
        for (int j = 0; j < 4; ++j) {
            int col = bn + tx * 4 + j;
            float v = acc[i][j];
            if (bias) v += b2f(bias[col]);
            if (mode == 1) v = 1.f / (1.f + __expf(-v));
            C[(long long)row * N + col] = f2b(v);
        }
    }
}

// ---------------- attention: one block per (local b, g, head) ----------------
__global__ void attn_kernel(const bf16* __restrict__ query,
                            const bf16* __restrict__ key_win, const bf16* __restrict__ key_glob,
                            const bf16* __restrict__ val_win, const bf16* __restrict__ val_glob,
                            bf16* __restrict__ attout) {
    int h = blockIdx.x & 7;
    int g = (blockIdx.x >> 3) & 63;
    int b = blockIdx.x >> 9;       // local batch within chunk
    int gy = g >> 3, gx = g & 7;

    __shared__ float qs[64][65];
    __shared__ bf16 ks[128][66];
    __shared__ bf16 vs[128][66];

    int tid = threadIdx.x;
    for (int i = tid; i < 64 * 64; i += 256) {
        int t = i >> 6, d = i & 63;
        int ty = t >> 3, tx = t & 7;
        long long row = (long long)b * NSP + (gy * 8 + ty) * WW + gx * 8 + tx;
        qs[t][d] = b2f(query[row * DD + h * 64 + d]);
    }
    for (int i = tid; i < 128 * 64; i += 256) {
        int t = i >> 6, d = i & 63;
        long long srow;
        const bf16 *kp, *vp;
        if (t < 64) {
            int ty = t >> 3, tx = t & 7;
            srow = (long long)b * NSP + (gy * 8 + ty) * WW + gx * 8 + tx;
            kp = key_win; vp = val_win;
        } else {
            srow = (long long)b * NM + (t - 64);
            kp = key_glob; vp = val_glob;
        }
        ks[t][d] = kp[srow * DD + h * 64 + d];
        vs[t][d] = vp[srow * DD + h * 64 + d];
    }
    __syncthreads();

    int qrow = tid >> 2;   // 0..63
    int part = tid & 3;    // 0..3, each owns 32 keys
    int k0 = part * 32;

    float qreg[64];
    #pragma unroll
    for (int d = 0; d < 64; ++d) qreg[d] = qs[qrow][d];

    float sc[32];
    float mx = -1e30f;
    #pragma unroll
    for (int kc = 0; kc < 32; ++kc) {
        float s = 0.f;
        #pragma unroll
        for (int d = 0; d < 64; ++d) s += qreg[d] * b2f(ks[k0 + kc][d]);
        s *= 0.125f;
        sc[kc] = s;
        mx = fmaxf(mx, s);
    }
    mx = fmaxf(mx, __shfl_xor(mx, 1, 64));
    mx = fmaxf(mx, __shfl_xor(mx, 2, 64));
    float l = 0.f;
    #pragma unroll
    for (int kc = 0; kc < 32; ++kc) { sc[kc] = __expf(sc[kc] - mx); l += sc[kc]; }
    l += __shfl_xor(l, 1, 64);
    l += __shfl_xor(l, 2, 64);
    float inv = 1.f / l;

    float outv[64];
    #pragma unroll
    for (int d = 0; d < 64; ++d) outv[d] = 0.f;
    #pragma unroll
    for (int kc = 0; kc < 32; ++kc) {
        float p = sc[kc];
        #pragma unroll
        for (int d = 0; d < 64; ++d) outv[d] += p * b2f(vs[k0 + kc][d]);
    }

    int ty = qrow >> 3, tx = qrow & 7;
    long long orow = (long long)b * NSP + (gy * 8 + ty) * WW + gx * 8 + tx;
    #pragma unroll
    for (int d = 0; d < 64; ++d) {
        float v = outv[d];
        v += __shfl_xor(v, 1, 64);
        v += __shfl_xor(v, 2, 64);
        if (part == 0) attout[orow * DD + h * 64 + d] = f2b(v * inv);
    }
}

static inline size_t alg(size_t b) { return (b + 255) & ~(size_t)255; }

extern "C" void kernel_launch(void* const* d_in, const int* in_sizes, int n_in,
                              void* d_out, int out_size, void* d_ws, size_t ws_size,
                              hipStream_t stream) {
    // index shift guard: if the scalar 't' was dropped from d_in, everything
    // after index 2 shifts down by one. Detect via in_sizes[2] (==1 iff t present).
    int s = (n_in > 2 && in_sizes[2] == 1) ? 0 : -1;

    const void* xv = d_in[0];
    const void* fv = d_in[1];
    const void* wsrc[NW];
    for (int i = 0; i < NW; ++i) wsrc[i] = d_in[3 + s + i];
    (void)out_size;

    // canonical weight table (dict order after t)
    const int wcnt[NW] = {327680, 512, 327680, 512, 262144, 512, 262144, 512,
                          40960, 640, 32768, 512, 640, 640, 640, 640, 512, 512,
                          81920, 128};
    WTab tab;
    int pre = 0;
    for (int i = 0; i < NW; ++i) {
        tab.src[i] = wsrc[i];
        tab.cnt[i] = wcnt[i];
        tab.pre[i] = pre;
        pre += wcnt[i];
    }
    tab.pre[NW] = pre;
    const int wtotal = pre;   // 1,342,208

    // ---- workspace layout ----
    char* ws = (char*)d_ws;
    size_t head = 0;
    int* flag = (int*)(ws + head); head += 256;
    bf16* wc = (bf16*)(ws + head); head += alg((size_t)wtotal * 2);

    // canonical weight pointers
    const bf16* Wq     = wc + tab.pre[0];
    const bf16* bq     = wc + tab.pre[1];
    const bf16* Wk     = wc + tab.pre[2];
    const bf16* bk     = wc + tab.pre[3];
    const bf16* Wv     = wc + tab.pre[4];
    const bf16* bv     = wc + tab.pre[5];
    const bf16* Wo     = wc + tab.pre[6];
    const bf16* bo     = wc + tab.pre[7];
    const bf16* convKw = wc + tab.pre[8];
    const bf16* convKb = wc + tab.pre[9];
    const bf16* convVw = wc + tab.pre[10];
    const bf16* convVb = wc + tab.pre[11];
    const bf16* qn_g   = wc + tab.pre[12];
    const bf16* qn_b   = wc + tab.pre[13];
    const bf16* kn_g   = wc + tab.pre[14];
    const bf16* kn_b   = wc + tab.pre[15];
    const bf16* vn_g   = wc + tab.pre[16];
    const bf16* vn_b   = wc + tab.pre[17];
    const bf16* rw_W   = wc + tab.pre[18];
    const bf16* rw_b   = wc + tab.pre[19];

    // per-batch chunk footprint
    const size_t sz_qk    = alg((size_t)NSP * IC * 2);   // also attout alias
    const size_t sz_big   = alg((size_t)NSP * DD * 2);   // query/key_win/val_win
    const size_t sz_kg    = alg((size_t)NM * IC * 2);
    const size_t sz_vg    = alg((size_t)NM * DD * 2);
    const size_t sz_stat  = alg((size_t)NSP * 2 * 4);
    const size_t sz_statg = alg((size_t)NM * 2 * 4);
    const size_t per_batch = sz_qk + 3 * sz_big + sz_kg + 3 * sz_vg + 2 * sz_stat + 2 * sz_statg;

    size_t avail = ws_size > head ? ws_size - head : 0;
    int nb = (int)(avail / per_batch);
    if (nb < 1) nb = 1;
    if (nb > BT) nb = BT;

    // ---- global prologue: dtype flag + canonical weights ----
    detect_dtype<<<1, 256, 0, stream>>>(xv, flag);
    convert_weights<<<(wtotal + 255) / 256, 256, 0, stream>>>(tab, flag, wc, wtotal);

    for (int b0 = 0; b0 < BT; b0 += nb) {
        int bc = BT - b0 < nb ? BT - b0 : nb;
        int rows = bc * NSP;

        size_t off = head;
        auto alloc = [&](size_t bytes) -> void* {
            void* p = ws + off; off += bytes; return p;
        };
        bf16* qk        = (bf16*)alloc(sz_qk * bc);
        bf16* query     = (bf16*)alloc(sz_big * bc);
        bf16* key_win   = (bf16*)alloc(sz_big * bc);
        bf16* val_win   = (bf16*)alloc(sz_big * bc);
        bf16* kg        = (bf16*)alloc(sz_kg * bc);
        bf16* vg        = (bf16*)alloc(sz_vg * bc);
        bf16* key_glob  = (bf16*)alloc(sz_vg * bc);
        bf16* val_glob  = (bf16*)alloc(sz_vg * bc);
        float* stats_qk = (float*)alloc(sz_stat * bc);
        float* stats_x  = (float*)alloc(sz_stat * bc);
        float* stats_kg = (float*)alloc(sz_statg * bc);
        float* stats_vg = (float*)alloc(sz_statg * bc);
        bf16* fw        = query;     // alias: fw dead before query written
        bf16* attout    = qk;        // alias: qk dead before attention
        bf16* outc      = key_win;   // alias: key_win dead after attention

        const void* xb = (const char*)xv + 0;  // adjusted below per dtype inside kernels
        const void* fb_;
        // byte offsets differ by dtype; pass element offsets via pointer math on both views
        // (we compute per-chunk base by elements; stride identical for both dtypes)
        // x chunk base: b0*NSP*DD elements ; f chunk: b0*NSP*CF elements
        // We form both candidate pointers; assemble_qk picks by flag. Use char math on
        // max-width (fp32) is wrong for bf16, so pass separately:
        const float* xb_f32 = (const float*)xv + (size_t)b0 * NSP * DD;
        const bf16*  xb_b16 = (const bf16*)xv + (size_t)b0 * NSP * DD;
        const float* fb_f32 = (const float*)fv + (size_t)b0 * NSP * CF;
        const bf16*  fb_b16 = (const bf16*)fv + (size_t)b0 * NSP * CF;
        (void)xb; (void)fb_;

        // 1. assemble qk = [x | f]  (dual dtype: pass both views, kernel selects)
        {
            long long total = (long long)rows * IC;
            int blocks = (int)((total + 255) / 256);
            // trick: pass the two views; flag picks. We reuse xv-style void* params.
            // To keep one kernel, we pass fp32 view pointers when flag==1 and bf16 when 0;
            // since we can't branch host-side on flag, the kernel gets BOTH base pointers
            // encoded: xv/fv point to element 0 of the chunk under each interpretation.
            // assemble_qk computes with the same element offset for either.
            assemble_qk<<<blocks, 256, 0, stream>>>(
                /*x fp32 view*/ (const void*)xb_f32, (const void*)fb_f32,
                flag, qk, rows);
            // NOTE: for bf16 path the fp32-view pointer is wrong; handle inside:
            // we instead pass bf16 views through a second launch? No — see kernel:
            // it casts the SAME pointer to float* or bf16*. xb_f32 == xv + b0*off*4
            // vs xb_b16 == xv + b0*off*2. These differ. Fix: launch with flag-agnostic
            // base = original xv/fv and add chunk offset inside the kernel.
            (void)xb_b16; (void)fb_b16;
        }
        // Correctness fix for chunk offset: re-run assemble with base pointers and
        // row offset folded in. (The launch above used fp32-view chunk bases; for the
        // bf16 case it's wrong, so we simply always launch with b0 folded as rows.)
        {
            long long total = (long long)rows * IC;
            int blocks = (int)((total + 255) / 256);
            // overwrite with the correct data for both dtypes:
            // pass ORIGINAL bases and let row index include b0 offset.
            struct Fold {};
            // Use a dedicated kernel launch: shift rows by passing pointers at element
            // granularity computed per-dtype INSIDE the kernel via flag:
            assemble_qk<<<blocks, 256, 0, stream>>>(
                (const void*)((const char*)xv), (const void*)((const char*)fv),
                flag, qk - 0, rows);
            // qk rows 0..rows-1 must map to global rows b0*NSP..; adjust by writing into
            // qk but reading global row = local + b0*NSP. assemble_qk doesn't know b0,
            // so instead we pre-offset the SOURCE pointers per dtype. Since that needs
            // flag, do it inside: we pass b0 via the rows parameter? Cleaner: dedicated
            // kernel below handles chunk offset properly. This launch is redundant for
            // chunk 0 only; for general b0 we use assemble_qk_off.
        }
        // Use the offset-aware assembly (the authoritative one; overwrites any
        // incorrect data from the launches above).
        {
            extern __global__ void assemble_qk_off(const void*, const void*, const int*,
                                                   bf16*, int, long long, long long);
            long long total = (long long)rows * IC;
            int blocks = (int)((total + 255) / 256);
            assemble_qk_off<<<blocks, 256, 0, stream>>>(
                xv, fv, flag, qk, rows,
                (long long)b0 * NSP * DD, (long long)b0 * NSP * CF);
        }
        // 2. flow gemm: fw = sigmoid(qk @ rw_W + rw_b)  (reads pre-reweight qk)
        gemm_ln<<<dim3(CF / TN, rows / TM), 256, 0, stream>>>(
            qk, IC, nullptr, nullptr, nullptr, rw_W, rw_b, fw, rows, CF, IC, 1);
        // 3. reweight f part of qk
        {
            long long total = (long long)rows * CF;
            reweight_f<<<(int)((total + 255) / 256), 256, 0, stream>>>(qk, fw, rows);
        }
        // 4. depthwise convs (V-conv reads original x = qk cols 0..511)
        dwconv_kernel<<<bc * NM, 256, 0, stream>>>(qk, IC, IC, convKw, convKb, kg);
        dwconv_kernel<<<bc * NM, 256, 0, stream>>>(qk, IC, DD, convVw, convVb, vg);
        // 5. LN stats
        stats_kernel<<<rows * 64 / 256, 256, 0, stream>>>(qk, IC, stats_qk, rows, IC);
        stats_kernel<<<rows * 64 / 256, 256, 0, stream>>>(qk, IC, stats_x, rows, DD);
        stats_kernel<<<bc * NM * 64 / 256, 256, 0, stream>>>(kg, IC, stats_kg, bc * NM, IC);
        stats_kernel<<<bc * NM * 64 / 256, 256, 0, stream>>>(vg, DD, stats_vg, bc * NM, DD);
        // 6. projections (LN fused into A load)
        gemm_ln<<<dim3(DD / TN, rows / TM), 256, 0, stream>>>(
            qk, IC, stats_qk, qn_g, qn_b, Wq, bq, query, rows, DD, IC, 0);
        gemm_ln<<<dim3(DD / TN, rows / TM), 256, 0, stream>>>(
            qk, IC, stats_qk, kn_g, kn_b, Wk, bk, key_win, rows, DD, IC, 0);
        gemm_ln<<<dim3(DD / TN, bc * NM / TM), 256, 0, stream>>>(
            kg, IC, stats_kg, kn_g, kn_b, Wk, bk, key_glob, bc * NM, DD, IC, 0);
        gemm_ln<<<dim3(DD / TN, rows / TM), 256, 0, stream>>>(
            qk, IC, stats_x, vn_g, vn_b, Wv, bv, val_win, rows, DD, DD, 0);
        gemm_ln<<<dim3(DD / TN, bc * NM / TM), 256, 0, stream>>>(
            vg, DD, stats_vg, vn_g, vn_b, Wv, bv, val_glob, bc * NM, DD, DD, 0);
        // 7. attention (attout aliases qk)
        attn_kernel<<<bc * NG * 8, 256, 0, stream>>>(query, key_win, key_glob,
                                                     val_win, val_glob, attout);
        // 8. output projection -> canonical bf16 (outc aliases key_win)
        gemm_ln<<<dim3(DD / TN, rows / TM), 256, 0, stream>>>(
            attout, DD, nullptr, nullptr, nullptr, Wo, bo, outc, rows, DD, DD, 0);
        // 9. store to d_out in detected dtype
        {
            long long n = (long long)rows * DD;
            int blocks = (int)((n + 255) / 256);
            if (blocks > 65535) blocks = 65535;
            store_out<<<blocks, 256, 0, stream>>>(outc, d_out, flag, n,
                                                  (long long)b0 * NSP * DD);
        }
    }
}

// offset-aware dual-dtype assembly (authoritative source-of-truth for qk)
__global__ void assemble_qk_off(const void* __restrict__ xv, const void* __restrict__ fv,
                                const int* __restrict__ flag, bf16* __restrict__ qk,
                                int rows, long long xoff, long long foff) {
    int fp32 = *flag;
    long long total = (long long)rows * IC;
    for (long long i = (long long)blockIdx.x * blockDim.x + threadIdx.x; i < total;
         i += (long long)gridDim.x * blockDim.x) {
        int row = (int)(i / IC);
        int c = (int)(i % IC);
        bf16 v;
        if (c < DD) {
            long long si = xoff + (long long)row * DD + c;
            v = fp32 ? f2b(((const float*)xv)[si]) : ((const bf16*)xv)[si];
        } else {
            long long si = foff + (long long)row * CF + (c - DD);
            v = fp32 ? f2b(((const float*)fv)[si]) : ((const bf16*)fv)[si];
        }
        qk[i] = v;
    }
}

// Round 4
// 1191.539 us; speedup vs baseline: 9.6668x; 9.6668x over previous
//
#include <hip/hip_runtime.h>
#include <hip/hip_bf16.h>

typedef __hip_bfloat16 bf16;
typedef __attribute__((ext_vector_type(8))) short bf16x8;
typedef __attribute__((ext_vector_type(8))) unsigned short ushort8;
typedef __attribute__((ext_vector_type(4))) unsigned short ushort4v;
typedef __attribute__((ext_vector_type(4))) float f32x4;

#define BT 8
#define HH 64
#define WW 64
#define NSP (HH*WW)          // 4096 spatial per batch
#define DD 512
#define CF 128
#define IC 640
#define NG 64                // windows per batch
#define NM 64                // global tokens per batch
#define EPS 1e-5f

static __device__ __forceinline__ float b2f(bf16 v) { return __bfloat162float(v); }
static __device__ __forceinline__ bf16 f2b(float v) { return __float2bfloat16(v); }
static __device__ __forceinline__ float u2f(unsigned short u) {
    return __uint_as_float((unsigned)u << 16);
}
static __device__ __forceinline__ unsigned short f2u(float v) {
    bf16 b = __float2bfloat16(v);
    return __builtin_bit_cast(unsigned short, b);
}

// ---------------- dtype detector ----------------
__global__ void detect_dtype(const void* __restrict__ x, int* __restrict__ flag) {
    __shared__ int cnt;
    if (threadIdx.x == 0) cnt = 0;
    __syncthreads();
    const unsigned* w = (const unsigned*)x;
    int local = 0;
    for (int i = threadIdx.x; i < 4096; i += 256) {
        float v = __uint_as_float(w[i]);
        float a = fabsf(v);
        if (a > 1e-5f && a < 1e4f) local++;
    }
    atomicAdd(&cnt, local);
    __syncthreads();
    if (threadIdx.x == 0) *flag = (cnt > 2048) ? 1 : 0;   // 1 = fp32, 0 = bf16
}

// ---------------- canonicalize weights to bf16 ----------------
#define NW 20
struct WTab {
    const void* src[NW];
    int pre[NW + 1];
};

__global__ void convert_weights(WTab t, const int* __restrict__ flag,
                                bf16* __restrict__ dst, int total) {
    int fp32 = *flag;
    for (int idx = blockIdx.x * blockDim.x + threadIdx.x; idx < total;
         idx += gridDim.x * blockDim.x) {
        int seg = 0;
        #pragma unroll
        for (int i = 0; i < NW; ++i) if (idx >= t.pre[i + 1]) seg = i + 1;
        int local = idx - t.pre[seg];
        bf16 v;
        if (fp32) v = f2b(((const float*)t.src[seg])[local]);
        else      v = ((const bf16*)t.src[seg])[local];
        dst[idx] = v;
    }
}

// ---------------- assemble qk = [x | f], dual dtype, chunk-offset ----------------
__global__ void assemble_qk_off(const void* __restrict__ xv, const void* __restrict__ fv,
                                const int* __restrict__ flag, bf16* __restrict__ qk,
                                int rows, long long xoff, long long foff) {
    int fp32 = *flag;
    long long total = (long long)rows * IC;
    for (long long i = (long long)blockIdx.x * blockDim.x + threadIdx.x; i < total;
         i += (long long)gridDim.x * blockDim.x) {
        int row = (int)(i / IC);
        int c = (int)(i % IC);
        bf16 v;
        if (c < DD) {
            long long si = xoff + (long long)row * DD + c;
            v = fp32 ? f2b(((const float*)xv)[si]) : ((const bf16*)xv)[si];
        } else {
            long long si = foff + (long long)row * CF + (c - DD);
            v = fp32 ? f2b(((const float*)fv)[si]) : ((const bf16*)fv)[si];
        }
        qk[i] = v;
    }
}

// ---------------- store output, dual dtype ----------------
__global__ void store_out(const bf16* __restrict__ outc, void* __restrict__ dout,
                          const int* __restrict__ flag, long long n, long long off) {
    int fp32 = *flag;
    for (long long i = (long long)blockIdx.x * blockDim.x + threadIdx.x; i < n;
         i += (long long)gridDim.x * blockDim.x) {
        if (fp32) ((float*)dout)[off + i] = b2f(outc[i]);
        else      ((bf16*)dout)[off + i] = outc[i];
    }
}

// ---------------- reweight ----------------
__global__ void reweight_f(bf16* __restrict__ qk, const bf16* __restrict__ fw, int rows) {
    long long i = (long long)blockIdx.x * blockDim.x + threadIdx.x;
    long long total = (long long)rows * CF;
    if (i >= total) return;
    int row = (int)(i / CF);
    int j = (int)(i % CF);
    long long qi = (long long)row * IC + DD + j;
    qk[qi] = f2b(b2f(qk[qi]) * b2f(fw[i]));
}

// ---------------- depthwise conv 8x8 stride 8 ----------------
__global__ void dwconv_kernel(const bf16* __restrict__ src, int ldr, int C,
                              const bf16* __restrict__ w, const bf16* __restrict__ bias,
                              bf16* __restrict__ dst) {
    int bm = blockIdx.x;
    int b = bm >> 6;
    int m = bm & 63;
    int my = m >> 3, mx = m & 7;
    const bf16* sb = src + (long long)b * NSP * ldr;
    for (int c = threadIdx.x; c < C; c += blockDim.x) {
        float acc = b2f(bias[c]);
        #pragma unroll
        for (int ky = 0; ky < 8; ++ky) {
            #pragma unroll
            for (int kx = 0; kx < 8; ++kx) {
                int pos = (my * 8 + ky) * WW + mx * 8 + kx;
                acc += b2f(sb[(long long)pos * ldr + c]) * b2f(w[c * 64 + ky * 8 + kx]);
            }
        }
        dst[(long long)bm * C + c] = f2b(acc);
    }
}

// ---------------- LN stats ----------------
__global__ void stats_kernel(const bf16* __restrict__ X, int lda, float* __restrict__ stats,
                             int rows, int K) {
    int gt = blockIdx.x * blockDim.x + threadIdx.x;
    int wid = gt >> 6;
    int lane = gt & 63;
    if (wid >= rows) return;
    const bf16* p = X + (long long)wid * lda;
    float s = 0.f, ss = 0.f;
    for (int k = lane; k < K; k += 64) {
        float v = b2f(p[k]);
        s += v; ss += v * v;
    }
    #pragma unroll
    for (int off = 32; off > 0; off >>= 1) {
        s  += __shfl_down(s,  off, 64);
        ss += __shfl_down(ss, off, 64);
    }
    if (lane == 0) {
        float m = s / K;
        float var = ss / K - m * m;
        stats[wid * 2]     = m;
        stats[wid * 2 + 1] = rsqrtf(var + EPS);
    }
}

// ---------------- vector GEMM (small M only) ----------------
#define TM 64
#define TN 64
#define TK 32
__global__ void gemm_ln(const bf16* __restrict__ A, int lda, const float* __restrict__ stats,
                        const bf16* __restrict__ lng, const bf16* __restrict__ lnb,
                        const bf16* __restrict__ B, const bf16* __restrict__ bias,
                        bf16* __restrict__ C, int M, int N, int K, int mode) {
    __shared__ float As[TK][TM + 1];
    __shared__ float Bs[TK][TN + 1];
    int bm = blockIdx.y * TM;
    int bn = blockIdx.x * TN;
    int tid = threadIdx.x;
    int tx = tid & 15, ty = tid >> 4;
    float acc[4][4] = {};
    for (int k0 = 0; k0 < K; k0 += TK) {
        #pragma unroll
        for (int i = 0; i < 8; ++i) {
            int idx = tid + i * 256;
            int r = idx >> 5, kk = idx & 31;
            int row = bm + r;
            int kg = k0 + kk;
            float a = b2f(A[(long long)row * lda + kg]);
            if (stats) {
                float mean = stats[row * 2], rstd = stats[row * 2 + 1];
                a = (a - mean) * rstd * b2f(lng[kg]) + b2f(lnb[kg]);
            }
            As[kk][r] = a;
        }
        #pragma unroll
        for (int i = 0; i < 8; ++i) {
            int idx = tid + i * 256;
            int kk = idx >> 6, c = idx & 63;
            Bs[kk][c] = b2f(B[(long long)(k0 + kk) * N + bn + c]);
        }
        __syncthreads();
        #pragma unroll
        for (int kk = 0; kk < TK; ++kk) {
            float ar[4], br[4];
            #pragma unroll
            for (int i = 0; i < 4; ++i) ar[i] = As[kk][ty * 4 + i];
            #pragma unroll
            for (int j = 0; j < 4; ++j) br[j] = Bs[kk][tx * 4 + j];
            #pragma unroll
            for (int i = 0; i < 4; ++i)
                #pragma unroll
                for (int j = 0; j < 4; ++j)
                    acc[i][j] += ar[i] * br[j];
        }
        __syncthreads();
    }
    #pragma unroll
    for (int i = 0; i < 4; ++i) {
        int row = bm + ty * 4 + i;
        #pragma unroll
        for (int j = 0; j < 4; ++j) {
            int col = bn + tx * 4 + j;
            float v = acc[i][j];
            if (bias) v += b2f(bias[col]);
            if (mode == 1) v = 1.f / (1.f + __expf(-v));
            C[(long long)row * N + col] = f2b(v);
        }
    }
}

// ---------------- MFMA GEMM: C[M,N] = LN(A) @ B + bias, M%128==0, N%128==0, K%32==0 ----
// 256 threads = 4 waves; each wave owns a 64x64 quadrant as 4x4 grid of 16x16 MFMA tiles.
#define GSTRIDE 40   // LDS row stride in bf16 (16B-aligned rows, ~2-way banking)
__global__ __launch_bounds__(256)
void gemm_mfma(const bf16* __restrict__ A, int lda, const float* __restrict__ stats,
               const bf16* __restrict__ lng, const bf16* __restrict__ lnb,
               const bf16* __restrict__ B, const bf16* __restrict__ bias,
               bf16* __restrict__ C, int M, int N, int K, int mode) {
    __shared__ unsigned short As[128][GSTRIDE];  // [m][k]
    __shared__ unsigned short Bs[128][GSTRIDE];  // [n][k] (transposed)
    int tid = threadIdx.x;
    int bm = blockIdx.y * 128;
    int bn = blockIdx.x * 128;
    int wave = tid >> 6, lane = tid & 63;
    int qm = (wave >> 1) * 64;
    int qn = (wave & 1) * 64;
    int lm = lane & 15;
    int kq = (lane >> 4) * 8;

    // A staging indices: thread -> (row r, half h)
    int ar = tid >> 1;          // 0..127
    int ah = (tid & 1) * 16;    // 0 or 16
    float mean = 0.f, rstd = 1.f;
    if (stats) {
        mean = stats[(bm + ar) * 2];
        rstd = stats[(bm + ar) * 2 + 1];
    }
    // B staging indices: thread -> (k row kk, col group c0)
    int bkk = tid >> 3;         // 0..31
    int bc0 = (tid & 7) * 16;   // 0..112

    f32x4 acc[4][4];
    #pragma unroll
    for (int i = 0; i < 4; ++i)
        #pragma unroll
        for (int j = 0; j < 4; ++j)
            acc[i][j] = (f32x4){0.f, 0.f, 0.f, 0.f};

    for (int k0 = 0; k0 < K; k0 += 32) {
        // ---- stage A (128x32) with fused LN ----
        {
            const unsigned short* ap =
                (const unsigned short*)A + (long long)(bm + ar) * lda + k0 + ah;
            ushort8 r0 = *(const ushort8*)ap;
            ushort8 r1 = *(const ushort8*)(ap + 8);
            ushort8 o0, o1;
            #pragma unroll
            for (int e = 0; e < 8; ++e) {
                int kg = k0 + ah + e;
                float a = u2f(r0[e]);
                if (stats) a = (a - mean) * rstd * b2f(lng[kg]) + b2f(lnb[kg]);
                o0[e] = f2u(a);
            }
            #pragma unroll
            for (int e = 0; e < 8; ++e) {
                int kg = k0 + ah + 8 + e;
                float a = u2f(r1[e]);
                if (stats) a = (a - mean) * rstd * b2f(lng[kg]) + b2f(lnb[kg]);
                o1[e] = f2u(a);
            }
            *(ushort8*)&As[ar][ah] = o0;
            *(ushort8*)&As[ar][ah + 8] = o1;
        }
        // ---- stage B (32x128) transposed ----
        {
            const unsigned short* bp =
                (const unsigned short*)B + (long long)(k0 + bkk) * N + bn + bc0;
            ushort8 r0 = *(const ushort8*)bp;
            ushort8 r1 = *(const ushort8*)(bp + 8);
            #pragma unroll
            for (int e = 0; e < 8; ++e) Bs[bc0 + e][bkk] = r0[e];
            #pragma unroll
            for (int e = 0; e < 8; ++e) Bs[bc0 + 8 + e][bkk] = r1[e];
        }
        __syncthreads();
        // ---- 16 MFMAs ----
        bf16x8 af[4], bf[4];
        #pragma unroll
        for (int i = 0; i < 4; ++i)
            af[i] = *(const bf16x8*)&As[qm + i * 16 + lm][kq];
        #pragma unroll
        for (int j = 0; j < 4; ++j)
            bf[j] = *(const bf16x8*)&Bs[qn + j * 16 + lm][kq];
        #pragma unroll
        for (int i = 0; i < 4; ++i)
            #pragma unroll
            for (int j = 0; j < 4; ++j)
                acc[i][j] = __builtin_amdgcn_mfma_f32_16x16x32_bf16(
                    af[i], bf[j], acc[i][j], 0, 0, 0);
        __syncthreads();
    }
    // ---- epilogue: C/D layout col=lane&15, row=(lane>>4)*4+reg ----
    int rq = (lane >> 4) * 4;
    #pragma unroll
    for (int i = 0; i < 4; ++i) {
        #pragma unroll
        for (int j = 0; j < 4; ++j) {
            int col = bn + qn + j * 16 + lm;
            float bv = bias ? b2f(bias[col]) : 0.f;
            #pragma unroll
            for (int r = 0; r < 4; ++r) {
                int row = bm + qm + i * 16 + rq + r;
                float v = acc[i][j][r] + bv;
                if (mode == 1) v = 1.f / (1.f + __expf(-v));
                C[(long long)row * N + col] = f2b(v);
            }
        }
    }
}

// ---------------- attention: spill-free, S in LDS ----------------
// block = (b_local, g, h); 256 threads.
__global__ __launch_bounds__(256)
void attn_kernel(const bf16* __restrict__ query,
                 const bf16* __restrict__ key_win, const bf16* __restrict__ key_glob,
                 const bf16* __restrict__ val_win, const bf16* __restrict__ val_glob,
                 bf16* __restrict__ attout) {
    int h = blockIdx.x & 7;
    int g = (blockIdx.x >> 3) & 63;
    int b = blockIdx.x >> 9;
    int gy = g >> 3, gx = g & 7;

    __shared__ unsigned short qs[64][66];    // [q][d]
    __shared__ unsigned short kv[128][66];   // K, later V
    __shared__ float S[64][133];             // scores / probs

    int tid = threadIdx.x;
    const unsigned short* Q  = (const unsigned short*)query;
    const unsigned short* KW = (const unsigned short*)key_win;
    const unsigned short* KG = (const unsigned short*)key_glob;
    const unsigned short* VW = (const unsigned short*)val_win;
    const unsigned short* VG = (const unsigned short*)val_glob;

    // load Q and K
    for (int i = tid; i < 64 * 64; i += 256) {
        int t = i >> 6, d = i & 63;
        int ty = t >> 3, tx = t & 7;
        long long row = (long long)b * NSP + (gy * 8 + ty) * WW + gx * 8 + tx;
        qs[t][d] = Q[row * DD + h * 64 + d];
    }
    for (int i = tid; i < 128 * 64; i += 256) {
        int t = i >> 6, d = i & 63;
        long long srow;
        const unsigned short* kp;
        if (t < 64) {
            int ty = t >> 3, tx = t & 7;
            srow = (long long)b * NSP + (gy * 8 + ty) * WW + gx * 8 + tx;
            kp = KW;
        } else {
            srow = (long long)b * NM + (t - 64);
            kp = KG;
        }
        kv[t][d] = kp[srow * DD + h * 64 + d];
    }
    __syncthreads();

    // phase A: S = Q K^T * 0.125 ; thread tile 4q x 8k (k strided by 16)
    {
        int tk = tid & 15;        // k base (stride-1 across lanes)
        int tqg = tid >> 4;       // 0..15
        int q0 = tqg * 4;
        float sacc[4][8];
        #pragma unroll
        for (int i = 0; i < 4; ++i)
            #pragma unroll
            for (int j = 0; j < 8; ++j) sacc[i][j] = 0.f;
        for (int d = 0; d < 64; ++d) {
            float a0 = u2f(qs[q0][d]), a1 = u2f(qs[q0 + 1][d]);
            float a2 = u2f(qs[q0 + 2][d]), a3 = u2f(qs[q0 + 3][d]);
            #pragma unroll
            for (int j = 0; j < 8; ++j) {
                float bb = u2f(kv[tk + 16 * j][d]);
                sacc[0][j] += a0 * bb;
                sacc[1][j] += a1 * bb;
                sacc[2][j] += a2 * bb;
                sacc[3][j] += a3 * bb;
            }
        }
        #pragma unroll
        for (int i = 0; i < 4; ++i)
            #pragma unroll
            for (int j = 0; j < 8; ++j)
                S[q0 + i][tk + 16 * j] = sacc[i][j] * 0.125f;
    }
    __syncthreads();

    // softmax over rows (4 lanes per row, 32 entries each) + load V into kv
    {
        int q = tid >> 2, seg = tid & 3;
        int c0 = seg * 32;
        float mx = -1e30f;
        #pragma unroll
        for (int c = 0; c < 32; ++c) mx = fmaxf(mx, S[q][c0 + c]);
        mx = fmaxf(mx, __shfl_xor(mx, 1, 64));
        mx = fmaxf(mx, __shfl_xor(mx, 2, 64));
        float l = 0.f;
        #pragma unroll
        for (int c = 0; c < 32; ++c) {
            float p = __expf(S[q][c0 + c] - mx);
            S[q][c0 + c] = p;
            l += p;
        }
        l += __shfl_xor(l, 1, 64);
        l += __shfl_xor(l, 2, 64);
        float inv = 1.f / l;
        #pragma unroll
        for (int c = 0; c < 32; ++c) S[q][c0 + c] *= inv;
    }
    // V load (kv reads of phase A complete; S fully rewritten before next barrier)
    __syncthreads();
    for (int i = tid; i < 128 * 64; i += 256) {
        int t = i >> 6, d = i & 63;
        long long srow;
        const unsigned short* vp;
        if (t < 64) {
            int ty = t >> 3, tx = t & 7;
            srow = (long long)b * NSP + (gy * 8 + ty) * WW + gx * 8 + tx;
            vp = VW;
        } else {
            srow = (long long)b * NM + (t - 64);
            vp = VG;
        }
        kv[t][d] = vp[srow * DD + h * 64 + d];
    }
    __syncthreads();

    // phase B: O = P V ; thread tile 4q x 4d
    {
        int td = tid & 15;
        int tqg = tid >> 4;
        int q0 = tqg * 4, d0 = td * 4;
        float oacc[4][4];
        #pragma unroll
        for (int i = 0; i < 4; ++i)
            #pragma unroll
            for (int j = 0; j < 4; ++j) oacc[i][j] = 0.f;
        for (int k = 0; k < 128; ++k) {
            float p0 = S[q0][k], p1 = S[q0 + 1][k];
            float p2 = S[q0 + 2][k], p3 = S[q0 + 3][k];
            #pragma unroll
            for (int j = 0; j < 4; ++j) {
                float vv = u2f(kv[k][d0 + j]);
                oacc[0][j] += p0 * vv;
                oacc[1][j] += p1 * vv;
                oacc[2][j] += p2 * vv;
                oacc[3][j] += p3 * vv;
            }
        }
        #pragma unroll
        for (int i = 0; i < 4; ++i) {
            int qrow = q0 + i;
            int ty = qrow >> 3, tx = qrow & 7;
            long long orow = (long long)b * NSP + (gy * 8 + ty) * WW + gx * 8 + tx;
            ushort4v pk;
            #pragma unroll
            for (int j = 0; j < 4; ++j) pk[j] = f2u(oacc[i][j]);
            *(ushort4v*)((unsigned short*)attout + orow * DD + h * 64 + d0) = pk;
        }
    }
}

static inline size_t alg(size_t b) { return (b + 255) & ~(size_t)255; }

extern "C" void kernel_launch(void* const* d_in, const int* in_sizes, int n_in,
                              void* d_out, int out_size, void* d_ws, size_t ws_size,
                              hipStream_t stream) {
    int s = (n_in > 2 && in_sizes[2] == 1) ? 0 : -1;

    const void* xv = d_in[0];
    const void* fv = d_in[1];
    const void* wsrc[NW];
    for (int i = 0; i < NW; ++i) wsrc[i] = d_in[3 + s + i];
    (void)out_size;

    const int wcnt[NW] = {327680, 512, 327680, 512, 262144, 512, 262144, 512,
                          40960, 640, 32768, 512, 640, 640, 640, 640, 512, 512,
                          81920, 128};
    WTab tab;
    int pre = 0;
    for (int i = 0; i < NW; ++i) {
        tab.src[i] = wsrc[i];
        tab.pre[i] = pre;
        pre += wcnt[i];
    }
    tab.pre[NW] = pre;
    const int wtotal = pre;

    char* ws = (char*)d_ws;
    size_t head = 0;
    int* flag = (int*)(ws + head); head += 256;
    bf16* wc = (bf16*)(ws + head); head += alg((size_t)wtotal * 2);

    const bf16* Wq     = wc + tab.pre[0];
    const bf16* bq     = wc + tab.pre[1];
    const bf16* Wk     = wc + tab.pre[2];
    const bf16* bk     = wc + tab.pre[3];
    const bf16* Wv     = wc + tab.pre[4];
    const bf16* bv     = wc + tab.pre[5];
    const bf16* Wo     = wc + tab.pre[6];
    const bf16* bo     = wc + tab.pre[7];
    const bf16* convKw = wc + tab.pre[8];
    const bf16* convKb = wc + tab.pre[9];
    const bf16* convVw = wc + tab.pre[10];
    const bf16* convVb = wc + tab.pre[11];
    const bf16* qn_g   = wc + tab.pre[12];
    const bf16* qn_b   = wc + tab.pre[13];
    const bf16* kn_g   = wc + tab.pre[14];
    const bf16* kn_b   = wc + tab.pre[15];
    const bf16* vn_g   = wc + tab.pre[16];
    const bf16* vn_b   = wc + tab.pre[17];
    const bf16* rw_W   = wc + tab.pre[18];
    const bf16* rw_b   = wc + tab.pre[19];

    const size_t sz_qk    = alg((size_t)NSP * IC * 2);
    const size_t sz_big   = alg((size_t)NSP * DD * 2);
    const size_t sz_kg    = alg((size_t)NM * IC * 2);
    const size_t sz_vg    = alg((size_t)NM * DD * 2);
    const size_t sz_stat  = alg((size_t)NSP * 2 * 4);
    const size_t sz_statg = alg((size_t)NM * 2 * 4);
    const size_t per_batch = sz_qk + 3 * sz_big + sz_kg + 3 * sz_vg + 2 * sz_stat + 2 * sz_statg;

    size_t avail = ws_size > head ? ws_size - head : 0;
    int nb = (int)(avail / per_batch);
    if (nb < 1) nb = 1;
    if (nb > BT) nb = BT;

    detect_dtype<<<1, 256, 0, stream>>>(xv, flag);
    convert_weights<<<(wtotal + 255) / 256, 256, 0, stream>>>(tab, flag, wc, wtotal);

    for (int b0 = 0; b0 < BT; b0 += nb) {
        int bc = BT - b0 < nb ? BT - b0 : nb;
        int rows = bc * NSP;

        size_t off = head;
        auto alloc = [&](size_t bytes) -> void* {
            void* p = ws + off; off += bytes; return p;
        };
        bf16* qk        = (bf16*)alloc(sz_qk * bc);
        bf16* query     = (bf16*)alloc(sz_big * bc);
        bf16* key_win   = (bf16*)alloc(sz_big * bc);
        bf16* val_win   = (bf16*)alloc(sz_big * bc);
        bf16* kg        = (bf16*)alloc(sz_kg * bc);
        bf16* vg        = (bf16*)alloc(sz_vg * bc);
        bf16* key_glob  = (bf16*)alloc(sz_vg * bc);
        bf16* val_glob  = (bf16*)alloc(sz_vg * bc);
        float* stats_qk = (float*)alloc(sz_stat * bc);
        float* stats_x  = (float*)alloc(sz_stat * bc);
        float* stats_kg = (float*)alloc(sz_statg * bc);
        float* stats_vg = (float*)alloc(sz_statg * bc);
        bf16* fw        = query;     // alias: fw dead before query written
        bf16* attout    = qk;        // alias: qk dead before attention
        bf16* outc      = key_win;   // alias: key_win dead after attention

        // 1. assemble qk = [x | f]
        {
            long long total = (long long)rows * IC;
            int blocks = (int)((total + 255) / 256);
            assemble_qk_off<<<blocks, 256, 0, stream>>>(
                xv, fv, flag, qk, rows,
                (long long)b0 * NSP * DD, (long long)b0 * NSP * CF);
        }
        // 2. flow gemm (MFMA): fw = sigmoid(qk @ rw_W + rw_b)
        gemm_mfma<<<dim3(CF / 128, rows / 128), 256, 0, stream>>>(
            qk, IC, nullptr, nullptr, nullptr, rw_W, rw_b, fw, rows, CF, IC, 1);
        // 3. reweight
        {
            long long total = (long long)rows * CF;
            reweight_f<<<(int)((total + 255) / 256), 256, 0, stream>>>(qk, fw, rows);
        }
        // 4. depthwise convs
        dwconv_kernel<<<bc * NM, 256, 0, stream>>>(qk, IC, IC, convKw, convKb, kg);
        dwconv_kernel<<<bc * NM, 256, 0, stream>>>(qk, IC, DD, convVw, convVb, vg);
        // 5. LN stats
        stats_kernel<<<rows * 64 / 256, 256, 0, stream>>>(qk, IC, stats_qk, rows, IC);
        stats_kernel<<<rows * 64 / 256, 256, 0, stream>>>(qk, IC, stats_x, rows, DD);
        stats_kernel<<<bc * NM * 64 / 256, 256, 0, stream>>>(kg, IC, stats_kg, bc * NM, IC);
        stats_kernel<<<bc * NM * 64 / 256, 256, 0, stream>>>(vg, DD, stats_vg, bc * NM, DD);
        // 6. projections (MFMA for big M, vector for global tokens)
        gemm_mfma<<<dim3(DD / 128, rows / 128), 256, 0, stream>>>(
            qk, IC, stats_qk, qn_g, qn_b, Wq, bq, query, rows, DD, IC, 0);
        gemm_mfma<<<dim3(DD / 128, rows / 128), 256, 0, stream>>>(
            qk, IC, stats_qk, kn_g, kn_b, Wk, bk, key_win, rows, DD, IC, 0);
        gemm_ln<<<dim3(DD / TN, bc * NM / TM), 256, 0, stream>>>(
            kg, IC, stats_kg, kn_g, kn_b, Wk, bk, key_glob, bc * NM, DD, IC, 0);
        gemm_mfma<<<dim3(DD / 128, rows / 128), 256, 0, stream>>>(
            qk, IC, stats_x, vn_g, vn_b, Wv, bv, val_win, rows, DD, DD, 0);
        gemm_ln<<<dim3(DD / TN, bc * NM / TM), 256, 0, stream>>>(
            vg, DD, stats_vg, vn_g, vn_b, Wv, bv, val_glob, bc * NM, DD, DD, 0);
        // 7. attention
        attn_kernel<<<bc * NG * 8, 256, 0, stream>>>(query, key_win, key_glob,
                                                     val_win, val_glob, attout);
        // 8. output projection (MFMA)
        gemm_mfma<<<dim3(DD / 128, rows / 128), 256, 0, stream>>>(
            attout, DD, nullptr, nullptr, nullptr, Wo, bo, outc, rows, DD, DD, 0);
        // 9. store
        {
            long long n = (long long)rows * DD;
            int blocks = (int)((n + 255) / 256);
            if (blocks > 65535) blocks = 65535;
            store_out<<<blocks, 256, 0, stream>>>(outc, d_out, flag, n,
                                                  (long long)b0 * NSP * DD);
        }
    }
}

// Round 6
// 1060.556 us; speedup vs baseline: 10.8606x; 1.1235x over previous
//
#include <hip/hip_runtime.h>
#include <hip/hip_bf16.h>

typedef __hip_bfloat16 bf16;
typedef __attribute__((ext_vector_type(8))) short bf16x8;
typedef __attribute__((ext_vector_type(8))) unsigned short ushort8;
typedef __attribute__((ext_vector_type(4))) float f32x4;

#define BT 8
#define HH 64
#define WW 64
#define NSP (HH*WW)          // 4096 spatial per batch
#define DD 512
#define CF 128
#define IC 640
#define NG 64                // windows per batch
#define NM 64                // global tokens per batch
#define EPS 1e-5f

static __device__ __forceinline__ float b2f(bf16 v) { return __bfloat162float(v); }
static __device__ __forceinline__ bf16 f2b(float v) { return __float2bfloat16(v); }
static __device__ __forceinline__ float u2f(unsigned short u) {
    return __uint_as_float((unsigned)u << 16);
}
static __device__ __forceinline__ unsigned short f2u(float v) {
    bf16 b = __float2bfloat16(v);
    return __builtin_bit_cast(unsigned short, b);
}

// ---------------- dtype detector ----------------
__global__ void detect_dtype(const void* __restrict__ x, int* __restrict__ flag) {
    __shared__ int cnt;
    if (threadIdx.x == 0) cnt = 0;
    __syncthreads();
    const unsigned* w = (const unsigned*)x;
    int local = 0;
    for (int i = threadIdx.x; i < 4096; i += 256) {
        float v = __uint_as_float(w[i]);
        float a = fabsf(v);
        if (a > 1e-5f && a < 1e4f) local++;
    }
    atomicAdd(&cnt, local);
    __syncthreads();
    if (threadIdx.x == 0) *flag = (cnt > 2048) ? 1 : 0;   // 1 = fp32, 0 = bf16
}

// ---------------- canonicalize weights to bf16 ----------------
#define NW 20
struct WTab {
    const void* src[NW];
    int pre[NW + 1];
};

__global__ void convert_weights(WTab t, const int* __restrict__ flag,
                                bf16* __restrict__ dst, int total) {
    int fp32 = *flag;
    for (int idx = blockIdx.x * blockDim.x + threadIdx.x; idx < total;
         idx += gridDim.x * blockDim.x) {
        int seg = 0;
        #pragma unroll
        for (int i = 0; i < NW; ++i) if (idx >= t.pre[i + 1]) seg = i + 1;
        int local = idx - t.pre[seg];
        bf16 v;
        if (fp32) v = f2b(((const float*)t.src[seg])[local]);
        else      v = ((const bf16*)t.src[seg])[local];
        dst[idx] = v;
    }
}

// ---------------- transpose the 5 GEMM weights: [K][N] -> [N][K] ----------------
struct TT {
    int srcoff[5], dstoff[5], R[5], C[5], tpre[6];
};
__global__ void transpose_weights(const bf16* __restrict__ wc, bf16* __restrict__ wt, TT t) {
    __shared__ unsigned short tile[32][33];
    int tb = blockIdx.x;
    int seg = 0;
    while (tb >= t.tpre[seg + 1]) seg++;
    int lt = tb - t.tpre[seg];
    int R = t.R[seg], C = t.C[seg];
    int tpr = C / 32;
    int r0 = (lt / tpr) * 32, c0 = (lt % tpr) * 32;
    const unsigned short* src = (const unsigned short*)(wc + t.srcoff[seg]);
    unsigned short* dst = (unsigned short*)(wt + t.dstoff[seg]);
    int tx = threadIdx.x & 31, ty = threadIdx.x >> 5;  // 32 x 8
    #pragma unroll
    for (int i = 0; i < 4; ++i)
        tile[ty + i * 8][tx] = src[(long long)(r0 + ty + i * 8) * C + c0 + tx];
    __syncthreads();
    #pragma unroll
    for (int i = 0; i < 4; ++i)
        dst[(long long)(c0 + ty + i * 8) * R + r0 + tx] = tile[tx][ty + i * 8];
}

// ---------------- assemble qk = [x | f], dual dtype, chunk-offset ----------------
__global__ void assemble_qk_off(const void* __restrict__ xv, const void* __restrict__ fv,
                                const int* __restrict__ flag, bf16* __restrict__ qk,
                                int rows, long long xoff, long long foff) {
    int fp32 = *flag;
    long long total = (long long)rows * IC;
    for (long long i = (long long)blockIdx.x * blockDim.x + threadIdx.x; i < total;
         i += (long long)gridDim.x * blockDim.x) {
        int row = (int)(i / IC);
        int c = (int)(i % IC);
        bf16 v;
        if (c < DD) {
            long long si = xoff + (long long)row * DD + c;
            v = fp32 ? f2b(((const float*)xv)[si]) : ((const bf16*)xv)[si];
        } else {
            long long si = foff + (long long)row * CF + (c - DD);
            v = fp32 ? f2b(((const float*)fv)[si]) : ((const bf16*)fv)[si];
        }
        qk[i] = v;
    }
}

// ---------------- store output, dual dtype ----------------
__global__ void store_out(const bf16* __restrict__ outc, void* __restrict__ dout,
                          const int* __restrict__ flag, long long n, long long off) {
    int fp32 = *flag;
    for (long long i = (long long)blockIdx.x * blockDim.x + threadIdx.x; i < n;
         i += (long long)gridDim.x * blockDim.x) {
        if (fp32) ((float*)dout)[off + i] = b2f(outc[i]);
        else      ((bf16*)dout)[off + i] = outc[i];
    }
}

// ---------------- reweight ----------------
__global__ void reweight_f(bf16* __restrict__ qk, const bf16* __restrict__ fw, int rows) {
    long long i = (long long)blockIdx.x * blockDim.x + threadIdx.x;
    long long total = (long long)rows * CF;
    if (i >= total) return;
    int row = (int)(i / CF);
    int j = (int)(i % CF);
    long long qi = (long long)row * IC + DD + j;
    qk[qi] = f2b(b2f(qk[qi]) * b2f(fw[i]));
}

// ---------------- depthwise conv 8x8 stride 8 ----------------
__global__ void dwconv_kernel(const bf16* __restrict__ src, int ldr, int C,
                              const bf16* __restrict__ w, const bf16* __restrict__ bias,
                              bf16* __restrict__ dst) {
    int bm = blockIdx.x;
    int b = bm >> 6;
    int m = bm & 63;
    int my = m >> 3, mx = m & 7;
    const bf16* sb = src + (long long)b * NSP * ldr;
    for (int c = threadIdx.x; c < C; c += blockDim.x) {
        float acc = b2f(bias[c]);
        #pragma unroll
        for (int ky = 0; ky < 8; ++ky) {
            #pragma unroll
            for (int kx = 0; kx < 8; ++kx) {
                int pos = (my * 8 + ky) * WW + mx * 8 + kx;
                acc += b2f(sb[(long long)pos * ldr + c]) * b2f(w[c * 64 + ky * 8 + kx]);
            }
        }
        dst[(long long)bm * C + c] = f2b(acc);
    }
}

// ---------------- LN stats ----------------
__global__ void stats_kernel(const bf16* __restrict__ X, int lda, float* __restrict__ stats,
                             int rows, int K) {
    int gt = blockIdx.x * blockDim.x + threadIdx.x;
    int wid = gt >> 6;
    int lane = gt & 63;
    if (wid >= rows) return;
    const bf16* p = X + (long long)wid * lda;
    float s = 0.f, ss = 0.f;
    for (int k = lane; k < K; k += 64) {
        float v = b2f(p[k]);
        s += v; ss += v * v;
    }
    #pragma unroll
    for (int off = 32; off > 0; off >>= 1) {
        s  += __shfl_down(s,  off, 64);
        ss += __shfl_down(ss, off, 64);
    }
    if (lane == 0) {
        float m = s / K;
        float var = ss / K - m * m;
        stats[wid * 2]     = m;
        stats[wid * 2 + 1] = rsqrtf(var + EPS);
    }
}

// ---------------- vector GEMM (small M only; B row-major [K][N]) ----------------
#define TM 64
#define TN 64
#define TK 32
__global__ void gemm_ln(const bf16* __restrict__ A, int lda, const float* __restrict__ stats,
                        const bf16* __restrict__ lng, const bf16* __restrict__ lnb,
                        const bf16* __restrict__ B, const bf16* __restrict__ bias,
                        bf16* __restrict__ C, int M, int N, int K, int mode) {
    __shared__ float As[TK][TM + 1];
    __shared__ float Bs[TK][TN + 1];
    int bm = blockIdx.y * TM;
    int bn = blockIdx.x * TN;
    int tid = threadIdx.x;
    int tx = tid & 15, ty = tid >> 4;
    float acc[4][4] = {};
    for (int k0 = 0; k0 < K; k0 += TK) {
        #pragma unroll
        for (int i = 0; i < 8; ++i) {
            int idx = tid + i * 256;
            int r = idx >> 5, kk = idx & 31;
            int row = bm + r;
            int kg = k0 + kk;
            float a = b2f(A[(long long)row * lda + kg]);
            if (stats) {
                float mean = stats[row * 2], rstd = stats[row * 2 + 1];
                a = (a - mean) * rstd * b2f(lng[kg]) + b2f(lnb[kg]);
            }
            As[kk][r] = a;
        }
        #pragma unroll
        for (int i = 0; i < 8; ++i) {
            int idx = tid + i * 256;
            int kk = idx >> 6, c = idx & 63;
            Bs[kk][c] = b2f(B[(long long)(k0 + kk) * N + bn + c]);
        }
        __syncthreads();
        #pragma unroll
        for (int kk = 0; kk < TK; ++kk) {
            float ar[4], br[4];
            #pragma unroll
            for (int i = 0; i < 4; ++i) ar[i] = As[kk][ty * 4 + i];
            #pragma unroll
            for (int j = 0; j < 4; ++j) br[j] = Bs[kk][tx * 4 + j];
            #pragma unroll
            for (int i = 0; i < 4; ++i)
                #pragma unroll
                for (int j = 0; j < 4; ++j)
                    acc[i][j] += ar[i] * br[j];
        }
        __syncthreads();
    }
    #pragma unroll
    for (int i = 0; i < 4; ++i) {
        int row = bm + ty * 4 + i;
        #pragma unroll
        for (int j = 0; j < 4; ++j) {
            int col = bn + tx * 4 + j;
            float v = acc[i][j];
            if (bias) v += b2f(bias[col]);
            if (mode == 1) v = 1.f / (1.f + __expf(-v));
            C[(long long)row * N + col] = f2b(v);
        }
    }
}

// ---------------- MFMA GEMM: C[M,N] = LN(A) @ B + bias ----------------
// B passed TRANSPOSED: Bmat is [N][K] row-major. M%128==0, N%128==0, K%32==0.
#define GSTRIDE 40
__global__ __launch_bounds__(256)
void gemm_mfma(const bf16* __restrict__ A, int lda, const float* __restrict__ stats,
               const bf16* __restrict__ lng, const bf16* __restrict__ lnb,
               const bf16* __restrict__ Bmat, const bf16* __restrict__ bias,
               bf16* __restrict__ C, int M, int N, int K, int mode) {
    __shared__ unsigned short As[128][GSTRIDE];  // [m][k]
    __shared__ unsigned short Bs[128][GSTRIDE];  // [n][k]
    int tid = threadIdx.x;
    int bm = blockIdx.y * 128;
    int bn = blockIdx.x * 128;
    int wave = tid >> 6, lane = tid & 63;
    int qm = (wave >> 1) * 64;
    int qn = (wave & 1) * 64;
    int lm = lane & 15;
    int kq = (lane >> 4) * 8;

    int ar = tid >> 1;          // 0..127 (row for A and Bmat staging)
    int ah = (tid & 1) * 16;    // 0 or 16
    float mean = 0.f, rstd = 1.f;
    if (stats) {
        mean = stats[(bm + ar) * 2];
        rstd = stats[(bm + ar) * 2 + 1];
    }

    f32x4 acc[4][4];
    #pragma unroll
    for (int i = 0; i < 4; ++i)
        #pragma unroll
        for (int j = 0; j < 4; ++j)
            acc[i][j] = (f32x4){0.f, 0.f, 0.f, 0.f};

    for (int k0 = 0; k0 < K; k0 += 32) {
        // ---- stage A (128x32) with fused LN ----
        {
            const unsigned short* ap =
                (const unsigned short*)A + (long long)(bm + ar) * lda + k0 + ah;
            ushort8 r0 = *(const ushort8*)ap;
            ushort8 r1 = *(const ushort8*)(ap + 8);
            ushort8 o0, o1;
            #pragma unroll
            for (int e = 0; e < 8; ++e) {
                int kg = k0 + ah + e;
                float a = u2f(r0[e]);
                if (stats) a = (a - mean) * rstd * b2f(lng[kg]) + b2f(lnb[kg]);
                o0[e] = f2u(a);
            }
            #pragma unroll
            for (int e = 0; e < 8; ++e) {
                int kg = k0 + ah + 8 + e;
                float a = u2f(r1[e]);
                if (stats) a = (a - mean) * rstd * b2f(lng[kg]) + b2f(lnb[kg]);
                o1[e] = f2u(a);
            }
            *(ushort8*)&As[ar][ah] = o0;
            *(ushort8*)&As[ar][ah + 8] = o1;
        }
        // ---- stage B (128 rows of Bmat x 32 k) — clean vector copy ----
        {
            const unsigned short* bp =
                (const unsigned short*)Bmat + (long long)(bn + ar) * K + k0 + ah;
            ushort8 r0 = *(const ushort8*)bp;
            ushort8 r1 = *(const ushort8*)(bp + 8);
            *(ushort8*)&Bs[ar][ah] = r0;
            *(ushort8*)&Bs[ar][ah + 8] = r1;
        }
        __syncthreads();
        // ---- 16 MFMAs ----
        bf16x8 af[4], bfr[4];
        #pragma unroll
        for (int i = 0; i < 4; ++i)
            af[i] = *(const bf16x8*)&As[qm + i * 16 + lm][kq];
        #pragma unroll
        for (int j = 0; j < 4; ++j)
            bfr[j] = *(const bf16x8*)&Bs[qn + j * 16 + lm][kq];
        #pragma unroll
        for (int i = 0; i < 4; ++i)
            #pragma unroll
            for (int j = 0; j < 4; ++j)
                acc[i][j] = __builtin_amdgcn_mfma_f32_16x16x32_bf16(
                    af[i], bfr[j], acc[i][j], 0, 0, 0);
        __syncthreads();
    }
    // ---- epilogue: C/D layout col=lane&15, row=(lane>>4)*4+reg ----
    int rq = (lane >> 4) * 4;
    #pragma unroll
    for (int i = 0; i < 4; ++i) {
        #pragma unroll
        for (int j = 0; j < 4; ++j) {
            int col = bn + qn + j * 16 + lm;
            float bv = bias ? b2f(bias[col]) : 0.f;
            #pragma unroll
            for (int r = 0; r < 4; ++r) {
                int row = bm + qm + i * 16 + rq + r;
                float v = acc[i][j][r] + bv;
                if (mode == 1) v = 1.f / (1.f + __expf(-v));
                C[(long long)row * N + col] = f2b(v);
            }
        }
    }
}

// ---------------- MFMA attention ----------------
// block = (b_local, g, h); 256 threads = 4 waves; wave w owns q-rows w*16..w*16+15.
// QK^T: M=64,N=128,K=64 ; softmax in registers ; PV: M=64,N=64,K=128.
#define QS_STRIDE 72
#define PS_STRIDE 136
__global__ __launch_bounds__(256)
void attn_kernel(const bf16* __restrict__ query,
                 const bf16* __restrict__ key_win, const bf16* __restrict__ key_glob,
                 const bf16* __restrict__ val_win, const bf16* __restrict__ val_glob,
                 bf16* __restrict__ attout) {
    int h = blockIdx.x & 7;
    int g = (blockIdx.x >> 3) & 63;
    int b = blockIdx.x >> 9;
    int gy = g >> 3, gx = g & 7;

    // phase 1: Qs[64][72] + Ks[128][72] = 13824 ushort
    // phase 2: Ps[64][136] + Vs[64][136] = 17408 ushort  (union)
    __shared__ unsigned short smem[64 * PS_STRIDE + 64 * PS_STRIDE];
    unsigned short* Qs = smem;                       // [64][QS_STRIDE]
    unsigned short* Ks = smem + 64 * QS_STRIDE;      // [128][QS_STRIDE]
    unsigned short* Ps = smem;                       // [64][PS_STRIDE]
    unsigned short* Vs = smem + 64 * PS_STRIDE;      // [64][PS_STRIDE] (d-major: [d][t])

    int tid = threadIdx.x;
    const unsigned short* Q  = (const unsigned short*)query;
    const unsigned short* KW = (const unsigned short*)key_win;
    const unsigned short* KG = (const unsigned short*)key_glob;
    const unsigned short* VW = (const unsigned short*)val_win;
    const unsigned short* VG = (const unsigned short*)val_glob;

    // ---- load Q (64x64) and K (128x64) as ushort8 ----
    #pragma unroll
    for (int it = 0; it < 2; ++it) {
        int i = tid + it * 256;        // 512 units
        int t = i >> 3, dg = (i & 7) * 8;
        int ty = t >> 3, tx = t & 7;
        long long row = (long long)b * NSP + (gy * 8 + ty) * WW + gx * 8 + tx;
        *(ushort8*)&Qs[t * QS_STRIDE + dg] = *(const ushort8*)&Q[row * DD + h * 64 + dg];
    }
    #pragma unroll
    for (int it = 0; it < 4; ++it) {
        int i = tid + it * 256;        // 1024 units
        int t = i >> 3, dg = (i & 7) * 8;
        long long srow;
        const unsigned short* kp;
        if (t < 64) {
            int ty = t >> 3, tx = t & 7;
            srow = (long long)b * NSP + (gy * 8 + ty) * WW + gx * 8 + tx;
            kp = KW;
        } else {
            srow = (long long)b * NM + (t - 64);
            kp = KG;
        }
        *(ushort8*)&Ks[t * QS_STRIDE + dg] = *(const ushort8*)&kp[srow * DD + h * 64 + dg];
    }
    __syncthreads();

    int wave = tid >> 6, lane = tid & 63;
    int m0 = wave * 16;
    int lm = lane & 15;
    int quad = lane >> 4;            // 0..3

    // ---- QK^T: wave computes S[m0..m0+15][0..127] ----
    f32x4 sacc[8];
    #pragma unroll
    for (int j = 0; j < 8; ++j) sacc[j] = (f32x4){0.f, 0.f, 0.f, 0.f};
    #pragma unroll
    for (int ks = 0; ks < 2; ++ks) {
        int kq = quad * 8 + ks * 32;
        bf16x8 af = *(const bf16x8*)&Qs[(m0 + lm) * QS_STRIDE + kq];
        #pragma unroll
        for (int j = 0; j < 8; ++j) {
            bf16x8 bfr = *(const bf16x8*)&Ks[(j * 16 + lm) * QS_STRIDE + kq];
            sacc[j] = __builtin_amdgcn_mfma_f32_16x16x32_bf16(af, bfr, sacc[j], 0, 0, 0);
        }
    }
    // ---- softmax in registers; rows = m0 + quad*4 + r, cols = j*16 + lm ----
    float pinv[4];
    #pragma unroll
    for (int r = 0; r < 4; ++r) {
        float mx = -1e30f;
        #pragma unroll
        for (int j = 0; j < 8; ++j) {
            sacc[j][r] *= 0.125f;
            mx = fmaxf(mx, sacc[j][r]);
        }
        mx = fmaxf(mx, __shfl_xor(mx, 1, 64));
        mx = fmaxf(mx, __shfl_xor(mx, 2, 64));
        mx = fmaxf(mx, __shfl_xor(mx, 4, 64));
        mx = fmaxf(mx, __shfl_xor(mx, 8, 64));
        float l = 0.f;
        #pragma unroll
        for (int j = 0; j < 8; ++j) {
            float p = __expf(sacc[j][r] - mx);
            sacc[j][r] = p;
            l += p;
        }
        l += __shfl_xor(l, 1, 64);
        l += __shfl_xor(l, 2, 64);
        l += __shfl_xor(l, 4, 64);
        l += __shfl_xor(l, 8, 64);
        pinv[r] = 1.f / l;
    }
    __syncthreads();   // all waves done reading Qs/Ks

    // ---- write P (bf16, [q][key]) and stage V transposed ([d][t]) ----
    #pragma unroll
    for (int r = 0; r < 4; ++r) {
        int qrow = m0 + quad * 4 + r;
        #pragma unroll
        for (int j = 0; j < 8; ++j)
            Ps[qrow * PS_STRIDE + j * 16 + lm] = f2u(sacc[j][r] * pinv[r]);
    }
    #pragma unroll
    for (int it = 0; it < 4; ++it) {
        int i = tid + it * 256;        // 1024 units: t=128, dg=8
        int t = i & 127, dg = (i >> 7) * 8;
        long long srow;
        const unsigned short* vp;
        if (t < 64) {
            int ty = t >> 3, tx = t & 7;
            srow = (long long)b * NSP + (gy * 8 + ty) * WW + gx * 8 + tx;
            vp = VW;
        } else {
            srow = (long long)b * NM + (t - 64);
            vp = VG;
        }
        ushort8 v = *(const ushort8*)&vp[srow * DD + h * 64 + dg];
        #pragma unroll
        for (int e = 0; e < 8; ++e) Vs[(dg + e) * PS_STRIDE + t] = v[e];
    }
    __syncthreads();

    // ---- PV: O[m0..m0+15][0..63] ----
    f32x4 oacc[4];
    #pragma unroll
    for (int j = 0; j < 4; ++j) oacc[j] = (f32x4){0.f, 0.f, 0.f, 0.f};
    #pragma unroll
    for (int ks = 0; ks < 4; ++ks) {
        int kq = quad * 8 + ks * 32;
        bf16x8 af = *(const bf16x8*)&Ps[(m0 + lm) * PS_STRIDE + kq];
        #pragma unroll
        for (int j = 0; j < 4; ++j) {
            bf16x8 bfr = *(const bf16x8*)&Vs[(j * 16 + lm) * PS_STRIDE + kq];
            oacc[j] = __builtin_amdgcn_mfma_f32_16x16x32_bf16(af, bfr, oacc[j], 0, 0, 0);
        }
    }
    // ---- epilogue: col(d)=j*16+lm, row(q)=m0+quad*4+r ----
    #pragma unroll
    for (int r = 0; r < 4; ++r) {
        int qrow = m0 + quad * 4 + r;
        int ty = qrow >> 3, tx = qrow & 7;
        long long orow = (long long)b * NSP + (gy * 8 + ty) * WW + gx * 8 + tx;
        unsigned short* op = (unsigned short*)attout + orow * DD + h * 64;
        #pragma unroll
        for (int j = 0; j < 4; ++j)
            op[j * 16 + lm] = f2u(oacc[j][r]);
    }
}

static inline size_t alg(size_t b) { return (b + 255) & ~(size_t)255; }

extern "C" void kernel_launch(void* const* d_in, const int* in_sizes, int n_in,
                              void* d_out, int out_size, void* d_ws, size_t ws_size,
                              hipStream_t stream) {
    int s = (n_in > 2 && in_sizes[2] == 1) ? 0 : -1;

    const void* xv = d_in[0];
    const void* fv = d_in[1];
    const void* wsrc[NW];
    for (int i = 0; i < NW; ++i) wsrc[i] = d_in[3 + s + i];
    (void)out_size;

    const int wcnt[NW] = {327680, 512, 327680, 512, 262144, 512, 262144, 512,
                          40960, 640, 32768, 512, 640, 640, 640, 640, 512, 512,
                          81920, 128};
    WTab tab;
    int pre = 0;
    for (int i = 0; i < NW; ++i) {
        tab.src[i] = wsrc[i];
        tab.pre[i] = pre;
        pre += wcnt[i];
    }
    tab.pre[NW] = pre;
    const int wtotal = pre;

    char* ws = (char*)d_ws;
    size_t head = 0;
    int* flag = (int*)(ws + head); head += 256;
    bf16* wc = (bf16*)(ws + head); head += alg((size_t)wtotal * 2);
    // transposed GEMM weights: Wq,Wk,Wv,Wo,rw_W
    const int wtcnt[5] = {327680, 327680, 262144, 262144, 81920};
    int wtoff[5], wtpre = 0;
    for (int i = 0; i < 5; ++i) { wtoff[i] = wtpre; wtpre += wtcnt[i]; }
    bf16* wt = (bf16*)(ws + head); head += alg((size_t)wtpre * 2);

    const bf16* bq     = wc + tab.pre[1];
    const bf16* Wk     = wc + tab.pre[2];
    const bf16* bk     = wc + tab.pre[3];
    const bf16* Wv     = wc + tab.pre[4];
    const bf16* bv     = wc + tab.pre[5];
    const bf16* bo     = wc + tab.pre[7];
    const bf16* convKw = wc + tab.pre[8];
    const bf16* convKb = wc + tab.pre[9];
    const bf16* convVw = wc + tab.pre[10];
    const bf16* convVb = wc + tab.pre[11];
    const bf16* qn_g   = wc + tab.pre[12];
    const bf16* qn_b   = wc + tab.pre[13];
    const bf16* kn_g   = wc + tab.pre[14];
    const bf16* kn_b   = wc + tab.pre[15];
    const bf16* vn_g   = wc + tab.pre[16];
    const bf16* vn_b   = wc + tab.pre[17];
    const bf16* rw_b   = wc + tab.pre[19];
    const bf16* WqT = wt + wtoff[0];
    const bf16* WkT = wt + wtoff[1];
    const bf16* WvT = wt + wtoff[2];
    const bf16* WoT = wt + wtoff[3];
    const bf16* rwT = wt + wtoff[4];

    const size_t sz_qk    = alg((size_t)NSP * IC * 2);
    const size_t sz_big   = alg((size_t)NSP * DD * 2);
    const size_t sz_kg    = alg((size_t)NM * IC * 2);
    const size_t sz_vg    = alg((size_t)NM * DD * 2);
    const size_t sz_stat  = alg((size_t)NSP * 2 * 4);
    const size_t sz_statg = alg((size_t)NM * 2 * 4);
    const size_t per_batch = sz_qk + 3 * sz_big + sz_kg + 3 * sz_vg + 2 * sz_stat + 2 * sz_statg;

    size_t avail = ws_size > head ? ws_size - head : 0;
    int nb = (int)(avail / per_batch);
    if (nb < 1) nb = 1;
    if (nb > BT) nb = BT;

    detect_dtype<<<1, 256, 0, stream>>>(xv, flag);
    convert_weights<<<(wtotal + 255) / 256, 256, 0, stream>>>(tab, flag, wc, wtotal);
    // transpose GEMM weights
    {
        TT tt;
        const int srcsel[5] = {0, 2, 4, 6, 18};
        const int Rr[5] = {IC, IC, DD, DD, IC};
        const int Cc[5] = {DD, DD, DD, DD, CF};
        int tp = 0;
        for (int i = 0; i < 5; ++i) {
            tt.srcoff[i] = tab.pre[srcsel[i]];
            tt.dstoff[i] = wtoff[i];
            tt.R[i] = Rr[i];
            tt.C[i] = Cc[i];
            tt.tpre[i] = tp;
            tp += (Rr[i] / 32) * (Cc[i] / 32);
        }
        tt.tpre[5] = tp;
        transpose_weights<<<tp, 256, 0, stream>>>(wc, wt, tt);
    }

    for (int b0 = 0; b0 < BT; b0 += nb) {
        int bc = BT - b0 < nb ? BT - b0 : nb;
        int rows = bc * NSP;

        size_t off = head;
        auto alloc = [&](size_t bytes) -> void* {
            void* p = ws + off; off += bytes; return p;
        };
        bf16* qk        = (bf16*)alloc(sz_qk * bc);
        bf16* query     = (bf16*)alloc(sz_big * bc);
        bf16* key_win   = (bf16*)alloc(sz_big * bc);
        bf16* val_win   = (bf16*)alloc(sz_big * bc);
        bf16* kg        = (bf16*)alloc(sz_kg * bc);
        bf16* vg        = (bf16*)alloc(sz_vg * bc);
        bf16* key_glob  = (bf16*)alloc(sz_vg * bc);
        bf16* val_glob  = (bf16*)alloc(sz_vg * bc);
        float* stats_qk = (float*)alloc(sz_stat * bc);
        float* stats_x  = (float*)alloc(sz_stat * bc);
        float* stats_kg = (float*)alloc(sz_statg * bc);
        float* stats_vg = (float*)alloc(sz_statg * bc);
        bf16* fw        = query;     // alias: fw dead before query written
        bf16* attout    = qk;        // alias: qk dead before attention
        bf16* outc      = key_win;   // alias: key_win dead after attention

        // 1. assemble qk = [x | f]
        {
            long long total = (long long)rows * IC;
            int blocks = (int)((total + 255) / 256);
            assemble_qk_off<<<blocks, 256, 0, stream>>>(
                xv, fv, flag, qk, rows,
                (long long)b0 * NSP * DD, (long long)b0 * NSP * CF);
        }
        // 2. flow gemm (MFMA): fw = sigmoid(qk @ rw_W + rw_b)
        gemm_mfma<<<dim3(CF / 128, rows / 128), 256, 0, stream>>>(
            qk, IC, nullptr, nullptr, nullptr, rwT, rw_b, fw, rows, CF, IC, 1);
        // 3. reweight
        {
            long long total = (long long)rows * CF;
            reweight_f<<<(int)((total + 255) / 256), 256, 0, stream>>>(qk, fw, rows);
        }
        // 4. depthwise convs
        dwconv_kernel<<<bc * NM, 256, 0, stream>>>(qk, IC, IC, convKw, convKb, kg);
        dwconv_kernel<<<bc * NM, 256, 0, stream>>>(qk, IC, DD, convVw, convVb, vg);
        // 5. LN stats
        stats_kernel<<<rows * 64 / 256, 256, 0, stream>>>(qk, IC, stats_qk, rows, IC);
        stats_kernel<<<rows * 64 / 256, 256, 0, stream>>>(qk, IC, stats_x, rows, DD);
        stats_kernel<<<bc * NM * 64 / 256, 256, 0, stream>>>(kg, IC, stats_kg, bc * NM, IC);
        stats_kernel<<<bc * NM * 64 / 256, 256, 0, stream>>>(vg, DD, stats_vg, bc * NM, DD);
        // 6. projections
        gemm_mfma<<<dim3(DD / 128, rows / 128), 256, 0, stream>>>(
            qk, IC, stats_qk, qn_g, qn_b, WqT, bq, query, rows, DD, IC, 0);
        gemm_mfma<<<dim3(DD / 128, rows / 128), 256, 0, stream>>>(
            qk, IC, stats_qk, kn_g, kn_b, WkT, bk, key_win, rows, DD, IC, 0);
        gemm_ln<<<dim3(DD / TN, bc * NM / TM), 256, 0, stream>>>(
            kg, IC, stats_kg, kn_g, kn_b, Wk, bk, key_glob, bc * NM, DD, IC, 0);
        gemm_mfma<<<dim3(DD / 128, rows / 128), 256, 0, stream>>>(
            qk, IC, stats_x, vn_g, vn_b, WvT, bv, val_win, rows, DD, DD, 0);
        gemm_ln<<<dim3(DD / TN, bc * NM / TM), 256, 0, stream>>>(
            vg, DD, stats_vg, vn_g, vn_b, Wv, bv, val_glob, bc * NM, DD, DD, 0);
        // 7. attention (MFMA)
        attn_kernel<<<bc * NG * 8, 256, 0, stream>>>(query, key_win, key_glob,
                                                     val_win, val_glob, attout);
        // 8. output projection (MFMA)
        gemm_mfma<<<dim3(DD / 128, rows / 128), 256, 0, stream>>>(
            attout, DD, nullptr, nullptr, nullptr, WoT, bo, outc, rows, DD, DD, 0);
        // 9. store
        {
            long long n = (long long)rows * DD;
            int blocks = (int)((n + 255) / 256);
            if (blocks > 65535) blocks = 65535;
            store_out<<<blocks, 256, 0, stream>>>(outc, d_out, flag, n,
                                                  (long long)b0 * NSP * DD);
        }
    }
}